// Round 3
// baseline (4393.498 us; speedup 1.0000x reference)
//
#include <hip/hip_runtime.h>
#include <hip/hip_bf16.h>

typedef __hip_bfloat16 bf16;

__device__ __forceinline__ float b2f(bf16 x) { return __bfloat162float(x); }
__device__ __forceinline__ bf16 f2b(float x) { return __float2bfloat16(x); }

// load element i from p; bf=1 -> bf16 storage, bf=0 -> f32 storage
__device__ __forceinline__ float ldf(const void* p, size_t i, int bf) {
    return bf ? b2f(((const bf16*)p)[i]) : ((const float*)p)[i];
}

#define BSZ 4
#define DM 1024
#define QLEN 512
#define MLEN 512
#define KLEN 1024
#define DI 4096
#define NH 16
#define DH 64
#define WIN 256   // local attention window: valid keys j = i+257 .. i+512

// ---- dtype detector: inspect low 16 bits of first 256 words of z1ss ----
// f32 data: low bits are random mantissa -> exp-field bits[14:7] uniform.
// bf16 data: low half is a bf16 of N(0,1) -> exp field in ~[100,150].
__global__ void detect_kernel(const unsigned* __restrict__ z, int* __restrict__ flag) {
    __shared__ int cnt;
    if (threadIdx.x == 0) cnt = 0;
    __syncthreads();
    unsigned w = z[threadIdx.x];
    unsigned e = (w >> 7) & 0xFFu;     // exponent field of the LOW bf16
    if (e >= 100 && e <= 150) atomicAdd(&cnt, 1);
    __syncthreads();
    if (threadIdx.x == 0) *flag = (cnt > 128) ? 1 : 0;   // 1 = inputs are bf16
}

// ---- generic tiled GEMM: C[b](bf16) = A @ B[b] + epilogue ----
// operand modes: *In=1 -> pointer is a d_in tensor (dtype = *flag), *In=0 -> ws bf16
__global__ __launch_bounds__(256) void gemm_kernel(
    const int* __restrict__ flag,
    const void* __restrict__ A,
    const void* __restrict__ B0, long sB0, int ldb0,
    const void* __restrict__ B1, long sB1, int ldb1, int b1In, int bsplit, int bcol,
    bf16* __restrict__ C, long sC,
    int M, int N, int K,
    const void* __restrict__ bias,
    const void* __restrict__ add, long sAdd, int addIn,
    int relu)
{
    int isbf = *flag;
    int abf = isbf;                 // A is always a d_in weight
    int b0bf = isbf;                // B0 (if present) is always d_in
    int b1bf = b1In ? isbf : 1;
    int addbf = addIn ? isbf : 1;
    int b = blockIdx.z;
    int tx = threadIdx.x;           // 0..31
    int ty = threadIdx.y;           // 0..7
    int row0 = blockIdx.y * 32, col0 = blockIdx.x * 32;
    __shared__ float As[32][33], Bs[32][33];
    float acc[4] = {0.f, 0.f, 0.f, 0.f};
    int c = col0 + tx;
    for (int kk = 0; kk < K; kk += 32) {
#pragma unroll
        for (int i = 0; i < 4; i++) {
            int r = ty + 8 * i;
            As[r][tx] = ldf(A, (size_t)(row0 + r) * K + kk + tx, abf);
            int k = kk + r;
            float bv;
            if (c < bsplit) bv = ldf(B0, (size_t)b * sB0 + (size_t)k * ldb0 + c, b0bf);
            else            bv = ldf(B1, (size_t)b * sB1 + (size_t)k * ldb1 + (c - bsplit) + bcol, b1bf);
            Bs[r][tx] = bv;
        }
        __syncthreads();
#pragma unroll
        for (int k = 0; k < 32; k++) {
            float bv = Bs[k][tx];
#pragma unroll
            for (int i = 0; i < 4; i++) acc[i] += As[ty + 8 * i][k] * bv;
        }
        __syncthreads();
    }
#pragma unroll
    for (int i = 0; i < 4; i++) {
        int r = row0 + ty + 8 * i;
        float v = acc[i];
        if (bias) v += ldf(bias, r, isbf);
        if (add)  v += ldf(add, (size_t)b * sAdd + (size_t)r * N + c, addbf);
        if (relu) v = fmaxf(v, 0.f);
        C[(size_t)b * sC + (size_t)r * N + c] = f2b(v);
    }
}

// ---- fused banded attention: one block per (i, n, b); 256 threads = 256 valid keys ----
__global__ __launch_bounds__(256) void attn_kernel(
    const int* __restrict__ flag,
    const bf16* __restrict__ WH,       // (BSZ, 3*DM, KLEN) ws
    const bf16* __restrict__ r_used,   // (DM, WIN) ws  (cols 768..1023 of r_head_k)
    const void* __restrict__ rwb, const void* __restrict__ rrb,
    bf16* __restrict__ attn_vec)       // (BSZ, DM, QLEN) ws
{
    int isbf = *flag;
    int i = blockIdx.x, n = blockIdx.y, b = blockIdx.z;
    const bf16* W = WH + (size_t)b * (3 * DM) * KLEN;
    __shared__ float qac[DH], qbd[DH], red[256], pj[256];
    int t = threadIdx.x;
    if (t < DH) {
        float qv = b2f(W[(size_t)(n * DH + t) * KLEN + MLEN + i]);  // q = last qlen cols
        qac[t] = qv + ldf(rwb, n * DH + t, isbf);
        qbd[t] = qv + ldf(rrb, n * DH + t, isbf);
    }
    __syncthreads();
    int j = i + WIN + 1 + t;   // valid key, <= 1023
    const bf16* krow = W + (size_t)(DM + n * DH) * KLEN;
    float s = 0.f;
#pragma unroll 8
    for (int d = 0; d < DH; d++) {
        s += qac[d] * b2f(krow[(size_t)d * KLEN + j]);
        s += qbd[d] * b2f(r_used[(size_t)(n * DH + d) * WIN + t]);  // rel idx 768+t
    }
    s *= 0.125f;  // 1/sqrt(64)
    red[t] = s; __syncthreads();
    for (int off = 128; off > 0; off >>= 1) {
        if (t < off) red[t] = fmaxf(red[t], red[t + off]);
        __syncthreads();
    }
    float mx = red[0]; __syncthreads();
    float e = __expf(s - mx);
    red[t] = e; __syncthreads();
    for (int off = 128; off > 0; off >>= 1) {
        if (t < off) red[t] += red[t + off];
        __syncthreads();
    }
    float p = e / red[0];
    pj[t] = p; __syncthreads();
    int d = t & 63, part = t >> 6;
    const bf16* vrow = W + (size_t)(2 * DM + n * DH + d) * KLEN + i + WIN + 1;
    float a = 0.f;
    int j0 = part * 64;
#pragma unroll 8
    for (int jj = j0; jj < j0 + 64; jj++) a += pj[jj] * b2f(vrow[jj]);
    red[t] = a; __syncthreads();
    if (part == 0) {
        float tot = red[d] + red[64 + d] + red[128 + d] + red[192 + d];
        attn_vec[(size_t)b * DM * QLEN + (size_t)(n * DH + d) * QLEN + i] = f2b(tot);
    }
}

// ---- layernorm over d_model (axis 1), per (b, column i) ----
// outIsOut=1 -> out is d_out (dtype follows flag); 0 -> ws bf16
__global__ __launch_bounds__(256) void ln_kernel(
    const int* __restrict__ flag,
    const bf16* __restrict__ P, void* __restrict__ out, int outIsOut)
{
    int isbf = *flag;
    int i = blockIdx.x, b = blockIdx.y, t = threadIdx.x;
    float s = 0.f, ss = 0.f;
    for (int d = t; d < DM; d += 256) {
        float v = b2f(P[(size_t)b * DM * QLEN + (size_t)d * QLEN + i]);
        s += v; ss += v * v;
    }
    __shared__ float r1[256], r2[256];
    r1[t] = s; r2[t] = ss; __syncthreads();
    for (int off = 128; off > 0; off >>= 1) {
        if (t < off) { r1[t] += r1[t + off]; r2[t] += r2[t + off]; }
        __syncthreads();
    }
    float m = r1[0] * (1.f / DM);
    float var = r2[0] * (1.f / DM) - m * m;
    float inv = rsqrtf(fmaxf(var, 0.f) + 1e-5f);
    int outbf = outIsOut ? isbf : 1;
    for (int d = t; d < DM; d += 256) {
        size_t off2 = (size_t)b * DM * QLEN + (size_t)d * QLEN + i;
        float v = (b2f(P[off2]) - m) * inv;
        if (outbf) ((bf16*)out)[off2] = f2b(v);
        else       ((float*)out)[off2] = v;
    }
}

extern "C" void kernel_launch(void* const* d_in, const int* in_sizes, int n_in,
                              void* d_out, int out_size, void* d_ws, size_t ws_size,
                              hipStream_t stream) {
    const void* z1ss  = d_in[0];
    const void* uss   = d_in[1];
    const void* z0    = d_in[2];
    const void* pos   = d_in[3];
    const void* qkv_w = d_in[4];
    const void* r_w   = d_in[5];
    const void* rwb   = d_in[6];
    const void* rrb   = d_in[7];
    const void* o_w   = d_in[8];
    const void* o_b   = d_in[9];
    const void* ff1_w = d_in[10];
    const void* ff1_b = d_in[11];
    const void* ff2_w = d_in[12];
    const void* ff2_b = d_in[13];

    bf16* ws = (bf16*)d_ws;
    bf16* w_heads  = ws;                                     // 4*3072*1024  (24 MiB)
    bf16* r_used   = w_heads + (size_t)BSZ * 3 * DM * KLEN;  // 1024*256    (0.5 MiB)
    bf16* attn_vec = r_used + (size_t)DM * WIN;              // 4*1024*512  (4 MiB)
    bf16* pre1     = attn_vec + (size_t)BSZ * DM * QLEN;     // 4*1024*512  (4 MiB)
    bf16* x        = pre1 + (size_t)BSZ * DM * QLEN;         // 4*1024*512  (4 MiB)
    bf16* h        = x + (size_t)BSZ * DM * QLEN;            // 4*4096*512  (16 MiB)
    bf16* pre2     = h + (size_t)BSZ * DI * QLEN;            // 4*1024*512  (4 MiB)
    int*  dflag    = (int*)(pre2 + (size_t)BSZ * DM * QLEN); // ~56.5 MiB total

    dim3 blk(32, 8);

    detect_kernel<<<1, 256, 0, stream>>>((const unsigned*)z1ss, dflag);

    // w_heads = qkv_w @ [z0 | z1ss] + uss   (M=3072, N=1024, K=1024, batch 4)
    gemm_kernel<<<dim3(KLEN / 32, (3 * DM) / 32, BSZ), blk, 0, stream>>>(
        dflag, qkv_w,
        z0, (long)DM * MLEN, MLEN,
        z1ss, (long)DM * QLEN, QLEN, 1, MLEN, 0,
        w_heads, (long)3 * DM * KLEN,
        3 * DM, KLEN, DM,
        nullptr, uss, (long)3 * DM * KLEN, 1, 0);

    // r_used = r_w @ pos_emb[:, 768:1024]   (M=1024, N=256, K=1024)
    gemm_kernel<<<dim3(WIN / 32, DM / 32, 1), blk, 0, stream>>>(
        dflag, r_w,
        nullptr, 0, 0,
        pos, 0, KLEN, 1, 0, KLEN - WIN,
        r_used, 0,
        DM, WIN, DM,
        nullptr, nullptr, 0, 0, 0);

    // fused banded attention -> attn_vec
    attn_kernel<<<dim3(QLEN, NH, BSZ), 256, 0, stream>>>(dflag, w_heads, r_used, rwb, rrb, attn_vec);

    // pre1 = o_w @ attn_vec + o_b + z1ss   (M=1024, N=512, K=1024)
    gemm_kernel<<<dim3(QLEN / 32, DM / 32, BSZ), blk, 0, stream>>>(
        dflag, o_w,
        nullptr, 0, 0,
        attn_vec, (long)DM * QLEN, QLEN, 0, 0, 0,
        pre1, (long)DM * QLEN,
        DM, QLEN, DM,
        o_b, z1ss, (long)DM * QLEN, 1, 0);

    // x = LN(pre1)
    ln_kernel<<<dim3(QLEN, BSZ), 256, 0, stream>>>(dflag, pre1, x, 0);

    // h = relu(ff1_w @ x + ff1_b)   (M=4096, N=512, K=1024)
    gemm_kernel<<<dim3(QLEN / 32, DI / 32, BSZ), blk, 0, stream>>>(
        dflag, ff1_w,
        nullptr, 0, 0,
        x, (long)DM * QLEN, QLEN, 0, 0, 0,
        h, (long)DI * QLEN,
        DI, QLEN, DM,
        ff1_b, nullptr, 0, 0, 1);

    // pre2 = ff2_w @ h + ff2_b + x   (M=1024, N=512, K=4096)
    gemm_kernel<<<dim3(QLEN / 32, DM / 32, BSZ), blk, 0, stream>>>(
        dflag, ff2_w,
        nullptr, 0, 0,
        h, (long)DI * QLEN, QLEN, 0, 0, 0,
        pre2, (long)DM * QLEN,
        DM, QLEN, DI,
        ff2_b, x, (long)DM * QLEN, 0, 0);

    // out = LN(pre2) -> d_out (dtype follows detected input dtype)
    ln_kernel<<<dim3(QLEN, BSZ), 256, 0, stream>>>(dflag, pre2, d_out, 1);
}

// Round 4
// 694.421 us; speedup vs baseline: 6.3268x; 6.3268x over previous
//
#include <hip/hip_runtime.h>
#include <hip/hip_bf16.h>

typedef unsigned short u16;
typedef __attribute__((ext_vector_type(8))) short s8v;
typedef __attribute__((ext_vector_type(4))) short s4v;
typedef __attribute__((ext_vector_type(4))) float f4v;

__device__ __forceinline__ float s2f(u16 s) {
    unsigned int u = ((unsigned int)s) << 16;
    return __builtin_bit_cast(float, u);
}
__device__ __forceinline__ u16 f2s(float f) {
    __hip_bfloat16 h = __float2bfloat16(f);
    return __builtin_bit_cast(u16, h);
}

#define BSZ 4
#define DM 1024
#define QLEN 512
#define MLEN 512
#define KLEN 1024
#define DI 4096
#define NH 16
#define DH 64
#define WIN 256   // valid keys: j = i+257 .. i+512

// ---- transpose f32 (feature-major) -> bf16 (position-major) ----
// dst[b*sD + (rowOff+t)*ldD + f] = src[b*sS + f*ldS + colOff + t]
__global__ __launch_bounds__(256) void trans_f2b(
    const float* __restrict__ src, long sS, int ldS, int colOff,
    u16* __restrict__ dst, long sD, int ldD, int rowOff)
{
    __shared__ float tile[32][33];
    int b = blockIdx.z;
    int t0 = blockIdx.x * 32, f0 = blockIdx.y * 32;
    int tx = threadIdx.x, ty = threadIdx.y;   // (32, 8)
#pragma unroll
    for (int p = 0; p < 4; ++p)
        tile[ty + 8 * p][tx] = src[(size_t)b * sS + (size_t)(f0 + ty + 8 * p) * ldS + colOff + t0 + tx];
    __syncthreads();
#pragma unroll
    for (int p = 0; p < 4; ++p)
        dst[(size_t)b * sD + (size_t)(rowOff + t0 + ty + 8 * p) * ldD + f0 + tx] = f2s(tile[tx][ty + 8 * p]);
}

// ---- transpose bf16 (position-major) -> f32 (feature-major) ----
// dst[b*sD + t*ldD + f] = src[b*sS + f*ldS + t]
__global__ __launch_bounds__(256) void trans_b2f(
    const u16* __restrict__ src, long sS, int ldS,
    float* __restrict__ dst, long sD, int ldD)
{
    __shared__ float tile[32][33];
    int b = blockIdx.z;
    int t0 = blockIdx.x * 32, f0 = blockIdx.y * 32;
    int tx = threadIdx.x, ty = threadIdx.y;
#pragma unroll
    for (int p = 0; p < 4; ++p)
        tile[ty + 8 * p][tx] = s2f(src[(size_t)b * sS + (size_t)(f0 + ty + 8 * p) * ldS + t0 + tx]);
    __syncthreads();
#pragma unroll
    for (int p = 0; p < 4; ++p)
        dst[(size_t)b * sD + (size_t)(t0 + ty + 8 * p) * ldD + f0 + tx] = tile[tx][ty + 8 * p];
}

// ---- MFMA GEMM: C^T[b](N x M, bf16) = A(M x K, f32) @ B^T[b](N x K, bf16) + epilogue ----
template<int BN>
__global__ __launch_bounds__(256) void gemm_mfma(
    const float* __restrict__ A,
    const u16* __restrict__ B, long sB,
    u16* __restrict__ C, long sC,
    int M, int K,
    const float* __restrict__ bias,
    const u16* __restrict__ addB, long sAddB,              // bf16 ws, [n*M + m]
    const float* __restrict__ addF, long sAddF, int ldF,   // f32 d_in, [m*ldF + n]
    int relu)
{
    constexpr int BM = 128, BK = 64;
    constexpr int MI = (BN == 128) ? 4 : 2;
    constexpr int NI = 4;
    const int b = blockIdx.z;
    const int col0 = blockIdx.x * BN;
    const int row0 = blockIdx.y * BM;
    const u16* Bp = B + (size_t)b * sB;
    __shared__ __align__(16) u16 As[BM * BK];
    __shared__ __align__(16) u16 Bs[BN * BK];
    const int tid = threadIdx.x;
    const int lane = tid & 63, wv = tid >> 6;
    const int l15 = lane & 15, quad = lane >> 4;
    const int wm = (BN == 128) ? (wv >> 1) * 64 : wv * 32;
    const int wn = (BN == 128) ? (wv & 1) * 64 : 0;
    f4v acc[MI][NI] = {};
    for (int kk = 0; kk < K; kk += BK) {
#pragma unroll
        for (int p = 0; p < (BM * BK) / (256 * 8); ++p) {
            int idx = p * 256 + tid;
            int r = idx >> 3, c = (idx & 7) * 8;
            const float* s = &A[(size_t)(row0 + r) * K + kk + c];
            f4v f0 = *(const f4v*)s, f1 = *(const f4v*)(s + 4);
            s8v w;
            w[0] = (short)f2s(f0[0]); w[1] = (short)f2s(f0[1]);
            w[2] = (short)f2s(f0[2]); w[3] = (short)f2s(f0[3]);
            w[4] = (short)f2s(f1[0]); w[5] = (short)f2s(f1[1]);
            w[6] = (short)f2s(f1[2]); w[7] = (short)f2s(f1[3]);
            *(s8v*)&As[r * BK + c] = w;
        }
#pragma unroll
        for (int p = 0; p < (BN * BK) / (256 * 8); ++p) {
            int idx = p * 256 + tid;
            int r = idx >> 3, c = (idx & 7) * 8;
            *(s8v*)&Bs[r * BK + c] = *(const s8v*)&Bp[(size_t)(col0 + r) * K + kk + c];
        }
        __syncthreads();
#pragma unroll
        for (int k0 = 0; k0 < BK; k0 += 32) {
            s8v af[MI], bfr[NI];
#pragma unroll
            for (int mi = 0; mi < MI; ++mi)
                af[mi] = *(const s8v*)&As[(wm + mi * 16 + l15) * BK + k0 + quad * 8];
#pragma unroll
            for (int ni = 0; ni < NI; ++ni)
                bfr[ni] = *(const s8v*)&Bs[(wn + ni * 16 + l15) * BK + k0 + quad * 8];
#pragma unroll
            for (int mi = 0; mi < MI; ++mi)
#pragma unroll
                for (int ni = 0; ni < NI; ++ni)
                    acc[mi][ni] = __builtin_amdgcn_mfma_f32_16x16x32_bf16(af[mi], bfr[ni], acc[mi][ni], 0, 0, 0);
        }
        __syncthreads();
    }
    u16* Cp = C + (size_t)b * sC;
#pragma unroll
    for (int mi = 0; mi < MI; ++mi) {
        int m = row0 + wm + mi * 16 + quad * 4;
        float bv[4] = {0.f, 0.f, 0.f, 0.f};
        if (bias) {
#pragma unroll
            for (int r2 = 0; r2 < 4; ++r2) bv[r2] = bias[m + r2];
        }
#pragma unroll
        for (int ni = 0; ni < NI; ++ni) {
            int n = col0 + wn + ni * 16 + l15;
            f4v v = acc[mi][ni];
            float o[4];
#pragma unroll
            for (int r2 = 0; r2 < 4; ++r2) o[r2] = v[r2] + bv[r2];
            if (addB) {
                s4v a4 = *(const s4v*)&addB[(size_t)b * sAddB + (size_t)n * M + m];
#pragma unroll
                for (int r2 = 0; r2 < 4; ++r2) o[r2] += s2f((u16)a4[r2]);
            }
            if (addF) {
#pragma unroll
                for (int r2 = 0; r2 < 4; ++r2)
                    o[r2] += addF[(size_t)b * sAddF + (size_t)(m + r2) * ldF + n];
            }
            if (relu) {
#pragma unroll
                for (int r2 = 0; r2 < 4; ++r2) o[r2] = fmaxf(o[r2], 0.f);
            }
            s4v st;
#pragma unroll
            for (int r2 = 0; r2 < 4; ++r2) st[r2] = (short)f2s(o[r2]);
            *(s4v*)&Cp[(size_t)n * M + m] = st;
        }
    }
}

// ---- fused banded attention, position-major ----
// block (i, b); 256 thr = 4 waves; wave wv owns window offsets t = wv*64..wv*64+63
__global__ __launch_bounds__(256) void attn_kernel(
    const u16* __restrict__ WHT,      // (BSZ, KLEN, 3*DM) bf16
    const u16* __restrict__ RT,       // (WIN, DM) bf16  (r_head_k cols 768..1023, transposed)
    const float* __restrict__ rwb, const float* __restrict__ rrb,   // (NH*DH) f32
    u16* __restrict__ avT)            // (BSZ, QLEN, DM) bf16
{
    int i = blockIdx.x, b = blockIdx.y;
    const u16* W = WHT + (size_t)b * KLEN * (3 * DM);
    __shared__ float qac[DM], qbd[DM];
    __shared__ float sm[NH][260];
    __shared__ float obuf[4][DM];
    int tid = threadIdx.x, lane = tid & 63, wv = tid >> 6;

    // load q (+biases) for query i
    {
        int f = tid * 4;
        s4v q4 = *(const s4v*)&W[(size_t)(MLEN + i) * (3 * DM) + f];
#pragma unroll
        for (int k = 0; k < 4; ++k) {
            float qv = s2f((u16)q4[k]);
            qac[f + k] = qv + rwb[f + k];
            qbd[f + k] = qv + rrb[f + k];
        }
    }
    __syncthreads();

    // hoist this lane's 16-feature slice to registers
    int f0 = lane * 16;
    float qa[16], qb[16];
#pragma unroll
    for (int e = 0; e < 16; ++e) { qa[e] = qac[f0 + e]; qb[e] = qbd[f0 + e]; }
    int n = lane >> 2;   // head owning this lane's slice

    // scores
    for (int jj = 0; jj < 64; ++jj) {
        int t = wv * 64 + jj;
        const u16* Krow = W + (size_t)(i + WIN + 1 + t) * (3 * DM) + DM;
        const u16* Rrow = RT + (size_t)t * DM;
        float s = 0.f;
#pragma unroll
        for (int c = 0; c < 2; ++c) {
            s8v kv = *(const s8v*)&Krow[f0 + c * 8];
            s8v rv = *(const s8v*)&Rrow[f0 + c * 8];
#pragma unroll
            for (int e = 0; e < 8; ++e) {
                s += qa[c * 8 + e] * s2f((u16)kv[e]);
                s += qb[c * 8 + e] * s2f((u16)rv[e]);
            }
        }
        s += __shfl_xor(s, 1, 64);
        s += __shfl_xor(s, 2, 64);
        if ((lane & 3) == 0) sm[n][t] = s * 0.125f;
    }
    __syncthreads();

    // softmax per head (wave wv handles heads 4*wv .. 4*wv+3)
#pragma unroll
    for (int hh = 0; hh < 4; ++hh) {
        int nh = wv * 4 + hh;
        f4v v = *(const f4v*)&sm[nh][lane * 4];
        float mx = fmaxf(fmaxf(v[0], v[1]), fmaxf(v[2], v[3]));
#pragma unroll
        for (int d = 1; d < 64; d <<= 1) mx = fmaxf(mx, __shfl_xor(mx, d, 64));
        f4v e;
#pragma unroll
        for (int k = 0; k < 4; ++k) e[k] = __expf(v[k] - mx);
        float sum = e[0] + e[1] + e[2] + e[3];
#pragma unroll
        for (int d = 1; d < 64; d <<= 1) sum += __shfl_xor(sum, d, 64);
        float inv = 1.f / sum;
#pragma unroll
        for (int k = 0; k < 4; ++k) e[k] *= inv;
        *(f4v*)&sm[nh][lane * 4] = e;
    }
    __syncthreads();

    // PV
    float acc[16];
#pragma unroll
    for (int e = 0; e < 16; ++e) acc[e] = 0.f;
    for (int jj = 0; jj < 64; ++jj) {
        int t = wv * 64 + jj;
        const u16* Vrow = W + (size_t)(i + WIN + 1 + t) * (3 * DM) + 2 * DM;
        float p = sm[n][t];
#pragma unroll
        for (int c = 0; c < 2; ++c) {
            s8v vv = *(const s8v*)&Vrow[f0 + c * 8];
#pragma unroll
            for (int e = 0; e < 8; ++e) acc[c * 8 + e] += p * s2f((u16)vv[e]);
        }
    }
#pragma unroll
    for (int c = 0; c < 4; ++c) {
        f4v o;
#pragma unroll
        for (int k = 0; k < 4; ++k) o[k] = acc[c * 4 + k];
        *(f4v*)&obuf[wv][f0 + c * 4] = o;
    }
    __syncthreads();
    {
        int f = tid * 4;
        f4v o0 = *(const f4v*)&obuf[0][f], o1 = *(const f4v*)&obuf[1][f];
        f4v o2 = *(const f4v*)&obuf[2][f], o3 = *(const f4v*)&obuf[3][f];
        s4v st;
#pragma unroll
        for (int k = 0; k < 4; ++k) st[k] = (short)f2s(o0[k] + o1[k] + o2[k] + o3[k]);
        *(s4v*)&avT[((size_t)b * QLEN + i) * DM + f] = st;
    }
}

// ---- layernorm over features (row-contiguous, position-major) ----
__global__ __launch_bounds__(256) void ln_kernel(const u16* __restrict__ P, u16* __restrict__ out)
{
    int q = blockIdx.x, b = blockIdx.y, tid = threadIdx.x;
    int lane = tid & 63, wv = tid >> 6;
    size_t base = ((size_t)b * QLEN + q) * DM;
    s4v v4 = *(const s4v*)&P[base + tid * 4];
    float v[4];
#pragma unroll
    for (int k = 0; k < 4; ++k) v[k] = s2f((u16)v4[k]);
    float s = v[0] + v[1] + v[2] + v[3];
    float ss = v[0] * v[0] + v[1] * v[1] + v[2] * v[2] + v[3] * v[3];
#pragma unroll
    for (int d = 1; d < 64; d <<= 1) {
        s += __shfl_xor(s, d, 64);
        ss += __shfl_xor(ss, d, 64);
    }
    __shared__ float ps[4], pss[4];
    if (lane == 0) { ps[wv] = s; pss[wv] = ss; }
    __syncthreads();
    float S = ps[0] + ps[1] + ps[2] + ps[3];
    float SS = pss[0] + pss[1] + pss[2] + pss[3];
    float m = S * (1.f / DM);
    float var = SS * (1.f / DM) - m * m;
    float inv = rsqrtf(fmaxf(var, 0.f) + 1e-5f);
    s4v st;
#pragma unroll
    for (int k = 0; k < 4; ++k) st[k] = (short)f2s((v[k] - m) * inv);
    *(s4v*)&out[base + tid * 4] = st;
}

extern "C" void kernel_launch(void* const* d_in, const int* in_sizes, int n_in,
                              void* d_out, int out_size, void* d_ws, size_t ws_size,
                              hipStream_t stream) {
    const float* z1ss  = (const float*)d_in[0];
    const float* uss   = (const float*)d_in[1];
    const float* z0    = (const float*)d_in[2];
    const float* pos   = (const float*)d_in[3];
    const float* qkv_w = (const float*)d_in[4];
    const float* r_w   = (const float*)d_in[5];
    const float* rwb   = (const float*)d_in[6];
    const float* rrb   = (const float*)d_in[7];
    const float* o_w   = (const float*)d_in[8];
    const float* o_b   = (const float*)d_in[9];
    const float* ff1_w = (const float*)d_in[10];
    const float* ff1_b = (const float*)d_in[11];
    const float* ff2_w = (const float*)d_in[12];
    const float* ff2_b = (const float*)d_in[13];

    u16* ws = (u16*)d_ws;
    u16* catT     = ws;                         // (4, 1024, 1024)  4M
    u16* avT      = ws + 4194304;               // (4, 512, 1024)   2M
    u16* pre1T    = ws + 6291456;               // (4, 512, 1024)   2M (reused as pre2T)
    u16* xT       = ws + 8388608;               // (4, 512, 1024)   2M
    u16* outT     = ws + 10485760;              // (4, 512, 1024)   2M
    u16* posT     = ws + 12582912;              // (256, 1024)      0.25M
    u16* rT       = ws + 12845056;              // (256, 1024)      0.25M
    u16* whT      = ws + 13107200;              // (4, 1024, 3072)  12M (reused as hT 8M)
    u16* hT       = whT;
    u16* pre2T    = pre1T;
    // total 25690112 u16 = ~51.4 MB

    dim3 tblk(32, 8);

    // catT[b][t][d]: t<512 from z0, t>=512 from z1ss
    trans_f2b<<<dim3(16, 32, BSZ), tblk, 0, stream>>>(z0, (long)DM * MLEN, MLEN, 0,
                                                      catT, (long)KLEN * DM, DM, 0);
    trans_f2b<<<dim3(16, 32, BSZ), tblk, 0, stream>>>(z1ss, (long)DM * QLEN, QLEN, 0,
                                                      catT, (long)KLEN * DM, DM, MLEN);
    // posT[t][d] = pos_emb[d][768+t]
    trans_f2b<<<dim3(8, 32, 1), tblk, 0, stream>>>(pos, 0, KLEN, KLEN - WIN,
                                                   posT, 0, DM, 0);

    // w_headsT[b][t][3072] = (qkv_w @ cat + uss)^T
    gemm_mfma<128><<<dim3(KLEN / 128, (3 * DM) / 128, BSZ), 256, 0, stream>>>(
        qkv_w, catT, (long)KLEN * DM, whT, (long)KLEN * 3 * DM,
        3 * DM, DM, nullptr, nullptr, 0, uss, (long)3 * DM * KLEN, KLEN, 0);

    // r_usedT[t][1024] = (r_w @ pos[:,768:1024])^T
    gemm_mfma<64><<<dim3(WIN / 64, DM / 128, 1), 256, 0, stream>>>(
        r_w, posT, 0, rT, 0,
        DM, DM, nullptr, nullptr, 0, nullptr, 0, 0, 0);

    // attention
    attn_kernel<<<dim3(QLEN, BSZ), 256, 0, stream>>>(whT, rT, rwb, rrb, avT);

    // pre1T = (o_w @ attn_vec + o_b + z1ss)^T
    gemm_mfma<64><<<dim3(QLEN / 64, DM / 128, BSZ), 256, 0, stream>>>(
        o_w, avT, (long)QLEN * DM, pre1T, (long)QLEN * DM,
        DM, DM, o_b, nullptr, 0, z1ss, (long)DM * QLEN, QLEN, 0);

    // xT = LN(pre1T)
    ln_kernel<<<dim3(QLEN, BSZ), 256, 0, stream>>>(pre1T, xT);

    // hT = relu(ff1_w @ x + ff1_b)^T
    gemm_mfma<128><<<dim3(QLEN / 128, DI / 128, BSZ), 256, 0, stream>>>(
        ff1_w, xT, (long)QLEN * DM, hT, (long)QLEN * DI,
        DI, DM, ff1_b, nullptr, 0, nullptr, 0, 0, 1);

    // pre2T = (ff2_w @ h + ff2_b)^T + xT
    gemm_mfma<64><<<dim3(QLEN / 64, DM / 128, BSZ), 256, 0, stream>>>(
        ff2_w, hT, (long)QLEN * DI, pre2T, (long)QLEN * DM,
        DM, DI, ff2_b, xT, (long)QLEN * DM, nullptr, 0, 0, 0);

    // outT = LN(pre2T)
    ln_kernel<<<dim3(QLEN, BSZ), 256, 0, stream>>>(pre2T, outT);

    // d_out[b][d][q] = outT[b][q][d]  (f32)
    trans_b2f<<<dim3(32, 16, BSZ), tblk, 0, stream>>>(outT, (long)QLEN * DM, DM,
                                                      (float*)d_out, (long)DM * QLEN, QLEN);
}

// Round 5
// 653.384 us; speedup vs baseline: 6.7242x; 1.0628x over previous
//
#include <hip/hip_runtime.h>
#include <hip/hip_bf16.h>

typedef unsigned short u16;
typedef __attribute__((ext_vector_type(8))) short s8v;
typedef __attribute__((ext_vector_type(4))) short s4v;
typedef __attribute__((ext_vector_type(4))) float f4v;

__device__ __forceinline__ float s2f(u16 s) {
    unsigned int u = ((unsigned int)s) << 16;
    return __builtin_bit_cast(float, u);
}
__device__ __forceinline__ u16 f2s(float f) {
    __hip_bfloat16 h = __float2bfloat16(f);
    return __builtin_bit_cast(u16, h);
}

#define BSZ 4
#define DM 1024
#define QLEN 512
#define MLEN 512
#define KLEN 1024
#define DI 4096
#define NH 16
#define DH 64
#define WIN 256   // valid keys: j = i+257 .. i+512

// ---- transpose f32 (feature-major) -> bf16 (position-major) ----
__global__ __launch_bounds__(256) void trans_f2b(
    const float* __restrict__ src, long sS, int ldS, int colOff,
    u16* __restrict__ dst, long sD, int ldD, int rowOff)
{
    __shared__ float tile[32][33];
    int b = blockIdx.z;
    int t0 = blockIdx.x * 32, f0 = blockIdx.y * 32;
    int tx = threadIdx.x, ty = threadIdx.y;   // (32, 8)
#pragma unroll
    for (int p = 0; p < 4; ++p)
        tile[ty + 8 * p][tx] = src[(size_t)b * sS + (size_t)(f0 + ty + 8 * p) * ldS + colOff + t0 + tx];
    __syncthreads();
#pragma unroll
    for (int p = 0; p < 4; ++p)
        dst[(size_t)b * sD + (size_t)(rowOff + t0 + ty + 8 * p) * ldD + f0 + tx] = f2s(tile[tx][ty + 8 * p]);
}

// ---- transpose bf16 (position-major) -> f32 (feature-major) ----
__global__ __launch_bounds__(256) void trans_b2f(
    const u16* __restrict__ src, long sS, int ldS,
    float* __restrict__ dst, long sD, int ldD)
{
    __shared__ float tile[32][33];
    int b = blockIdx.z;
    int t0 = blockIdx.x * 32, f0 = blockIdx.y * 32;
    int tx = threadIdx.x, ty = threadIdx.y;
#pragma unroll
    for (int p = 0; p < 4; ++p)
        tile[ty + 8 * p][tx] = s2f(src[(size_t)b * sS + (size_t)(f0 + ty + 8 * p) * ldS + t0 + tx]);
    __syncthreads();
#pragma unroll
    for (int p = 0; p < 4; ++p)
        dst[(size_t)b * sD + (size_t)(t0 + ty + 8 * p) * ldD + f0 + tx] = tile[tx][ty + 8 * p];
}

// ---- MFMA GEMM: C^T[b](N x M, bf16) = A(M x K, f32) @ B^T[b](N x K, bf16) + epilogue ----
// LDS rows padded +8 u16: row stride 144 B (9x16B) -> frag reads 2-way aliased (free),
// staging writes at minimum aliasing. (r4: unpadded 128B rows = full bank wrap = 16-way.)
template<int BN>
__global__ __launch_bounds__(256) void gemm_mfma(
    const float* __restrict__ A,
    const u16* __restrict__ B, long sB,
    u16* __restrict__ C, long sC,
    int M, int K,
    const float* __restrict__ bias,
    const u16* __restrict__ addB, long sAddB,              // bf16 ws, [n*M + m]
    const float* __restrict__ addF, long sAddF, int ldF,   // f32 d_in, [m*ldF + n]
    int relu)
{
    constexpr int BM = 128, BK = 64, BKP = BK + 8;
    constexpr int MI = (BN == 128) ? 4 : 2;
    constexpr int NI = 4;
    const int b = blockIdx.z;
    const int col0 = blockIdx.x * BN;
    const int row0 = blockIdx.y * BM;
    const u16* Bp = B + (size_t)b * sB;
    __shared__ __align__(16) u16 As[BM * BKP];
    __shared__ __align__(16) u16 Bs[BN * BKP];
    const int tid = threadIdx.x;
    const int lane = tid & 63, wv = tid >> 6;
    const int l15 = lane & 15, quad = lane >> 4;
    const int wm = (BN == 128) ? (wv >> 1) * 64 : wv * 32;
    const int wn = (BN == 128) ? (wv & 1) * 64 : 0;
    f4v acc[MI][NI] = {};
    for (int kk = 0; kk < K; kk += BK) {
#pragma unroll
        for (int p = 0; p < (BM * BK) / (256 * 8); ++p) {
            int idx = p * 256 + tid;
            int r = idx >> 3, c = (idx & 7) * 8;
            const float* s = &A[(size_t)(row0 + r) * K + kk + c];
            f4v f0 = *(const f4v*)s, f1 = *(const f4v*)(s + 4);
            s8v w;
            w[0] = (short)f2s(f0[0]); w[1] = (short)f2s(f0[1]);
            w[2] = (short)f2s(f0[2]); w[3] = (short)f2s(f0[3]);
            w[4] = (short)f2s(f1[0]); w[5] = (short)f2s(f1[1]);
            w[6] = (short)f2s(f1[2]); w[7] = (short)f2s(f1[3]);
            *(s8v*)&As[r * BKP + c] = w;
        }
#pragma unroll
        for (int p = 0; p < (BN * BK) / (256 * 8); ++p) {
            int idx = p * 256 + tid;
            int r = idx >> 3, c = (idx & 7) * 8;
            *(s8v*)&Bs[r * BKP + c] = *(const s8v*)&Bp[(size_t)(col0 + r) * K + kk + c];
        }
        __syncthreads();
#pragma unroll
        for (int k0 = 0; k0 < BK; k0 += 32) {
            s8v af[MI], bfr[NI];
#pragma unroll
            for (int mi = 0; mi < MI; ++mi)
                af[mi] = *(const s8v*)&As[(wm + mi * 16 + l15) * BKP + k0 + quad * 8];
#pragma unroll
            for (int ni = 0; ni < NI; ++ni)
                bfr[ni] = *(const s8v*)&Bs[(wn + ni * 16 + l15) * BKP + k0 + quad * 8];
#pragma unroll
            for (int mi = 0; mi < MI; ++mi)
#pragma unroll
                for (int ni = 0; ni < NI; ++ni)
                    acc[mi][ni] = __builtin_amdgcn_mfma_f32_16x16x32_bf16(af[mi], bfr[ni], acc[mi][ni], 0, 0, 0);
        }
        __syncthreads();
    }
    u16* Cp = C + (size_t)b * sC;
#pragma unroll
    for (int mi = 0; mi < MI; ++mi) {
        int m = row0 + wm + mi * 16 + quad * 4;
        float bv[4] = {0.f, 0.f, 0.f, 0.f};
        if (bias) {
#pragma unroll
            for (int r2 = 0; r2 < 4; ++r2) bv[r2] = bias[m + r2];
        }
#pragma unroll
        for (int ni = 0; ni < NI; ++ni) {
            int n = col0 + wn + ni * 16 + l15;
            f4v v = acc[mi][ni];
            float o[4];
#pragma unroll
            for (int r2 = 0; r2 < 4; ++r2) o[r2] = v[r2] + bv[r2];
            if (addB) {
                s4v a4 = *(const s4v*)&addB[(size_t)b * sAddB + (size_t)n * M + m];
#pragma unroll
                for (int r2 = 0; r2 < 4; ++r2) o[r2] += s2f((u16)a4[r2]);
            }
            if (addF) {
#pragma unroll
                for (int r2 = 0; r2 < 4; ++r2)
                    o[r2] += addF[(size_t)b * sAddF + (size_t)(m + r2) * ldF + n];
            }
            if (relu) {
#pragma unroll
                for (int r2 = 0; r2 < 4; ++r2) o[r2] = fmaxf(o[r2], 0.f);
            }
            s4v st;
#pragma unroll
            for (int r2 = 0; r2 < 4; ++r2) st[r2] = (short)f2s(o[r2]);
            *(s4v*)&Cp[(size_t)n * M + m] = st;
        }
    }
}

// ---- fused banded attention, position-major ----
__global__ __launch_bounds__(256) void attn_kernel(
    const u16* __restrict__ WHT,      // (BSZ, KLEN, 3*DM) bf16
    const u16* __restrict__ RT,       // (WIN, DM) bf16
    const float* __restrict__ rwb, const float* __restrict__ rrb,
    u16* __restrict__ avT)            // (BSZ, QLEN, DM) bf16
{
    int i = blockIdx.x, b = blockIdx.y;
    const u16* W = WHT + (size_t)b * KLEN * (3 * DM);
    __shared__ float qac[DM], qbd[DM];
    __shared__ float sm[NH][260];
    __shared__ float obuf[4][DM];
    int tid = threadIdx.x, lane = tid & 63, wv = tid >> 6;

    {
        int f = tid * 4;
        s4v q4 = *(const s4v*)&W[(size_t)(MLEN + i) * (3 * DM) + f];
#pragma unroll
        for (int k = 0; k < 4; ++k) {
            float qv = s2f((u16)q4[k]);
            qac[f + k] = qv + rwb[f + k];
            qbd[f + k] = qv + rrb[f + k];
        }
    }
    __syncthreads();

    int f0 = lane * 16;
    float qa[16], qb[16];
#pragma unroll
    for (int e = 0; e < 16; ++e) { qa[e] = qac[f0 + e]; qb[e] = qbd[f0 + e]; }
    int n = lane >> 2;

    for (int jj = 0; jj < 64; ++jj) {
        int t = wv * 64 + jj;
        const u16* Krow = W + (size_t)(i + WIN + 1 + t) * (3 * DM) + DM;
        const u16* Rrow = RT + (size_t)t * DM;
        float s = 0.f;
#pragma unroll
        for (int c = 0; c < 2; ++c) {
            s8v kv = *(const s8v*)&Krow[f0 + c * 8];
            s8v rv = *(const s8v*)&Rrow[f0 + c * 8];
#pragma unroll
            for (int e = 0; e < 8; ++e) {
                s += qa[c * 8 + e] * s2f((u16)kv[e]);
                s += qb[c * 8 + e] * s2f((u16)rv[e]);
            }
        }
        s += __shfl_xor(s, 1, 64);
        s += __shfl_xor(s, 2, 64);
        if ((lane & 3) == 0) sm[n][t] = s * 0.125f;
    }
    __syncthreads();

#pragma unroll
    for (int hh = 0; hh < 4; ++hh) {
        int nh = wv * 4 + hh;
        f4v v = *(const f4v*)&sm[nh][lane * 4];
        float mx = fmaxf(fmaxf(v[0], v[1]), fmaxf(v[2], v[3]));
#pragma unroll
        for (int d = 1; d < 64; d <<= 1) mx = fmaxf(mx, __shfl_xor(mx, d, 64));
        f4v e;
#pragma unroll
        for (int k = 0; k < 4; ++k) e[k] = __expf(v[k] - mx);
        float sum = e[0] + e[1] + e[2] + e[3];
#pragma unroll
        for (int d = 1; d < 64; d <<= 1) sum += __shfl_xor(sum, d, 64);
        float inv = 1.f / sum;
#pragma unroll
        for (int k = 0; k < 4; ++k) e[k] *= inv;
        *(f4v*)&sm[nh][lane * 4] = e;
    }
    __syncthreads();

    float acc[16];
#pragma unroll
    for (int e = 0; e < 16; ++e) acc[e] = 0.f;
    for (int jj = 0; jj < 64; ++jj) {
        int t = wv * 64 + jj;
        const u16* Vrow = W + (size_t)(i + WIN + 1 + t) * (3 * DM) + 2 * DM;
        float p = sm[n][t];
#pragma unroll
        for (int c = 0; c < 2; ++c) {
            s8v vv = *(const s8v*)&Vrow[f0 + c * 8];
#pragma unroll
            for (int e = 0; e < 8; ++e) acc[c * 8 + e] += p * s2f((u16)vv[e]);
        }
    }
#pragma unroll
    for (int c = 0; c < 4; ++c) {
        f4v o;
#pragma unroll
        for (int k = 0; k < 4; ++k) o[k] = acc[c * 4 + k];
        *(f4v*)&obuf[wv][f0 + c * 4] = o;
    }
    __syncthreads();
    {
        int f = tid * 4;
        f4v o0 = *(const f4v*)&obuf[0][f], o1 = *(const f4v*)&obuf[1][f];
        f4v o2 = *(const f4v*)&obuf[2][f], o3 = *(const f4v*)&obuf[3][f];
        s4v st;
#pragma unroll
        for (int k = 0; k < 4; ++k) st[k] = (short)f2s(o0[k] + o1[k] + o2[k] + o3[k]);
        *(s4v*)&avT[((size_t)b * QLEN + i) * DM + f] = st;
    }
}

// ---- layernorm over features (row-contiguous, position-major) ----
__global__ __launch_bounds__(256) void ln_kernel(const u16* __restrict__ P, u16* __restrict__ out)
{
    int q = blockIdx.x, b = blockIdx.y, tid = threadIdx.x;
    int lane = tid & 63, wv = tid >> 6;
    size_t base = ((size_t)b * QLEN + q) * DM;
    s4v v4 = *(const s4v*)&P[base + tid * 4];
    float v[4];
#pragma unroll
    for (int k = 0; k < 4; ++k) v[k] = s2f((u16)v4[k]);
    float s = v[0] + v[1] + v[2] + v[3];
    float ss = v[0] * v[0] + v[1] * v[1] + v[2] * v[2] + v[3] * v[3];
#pragma unroll
    for (int d = 1; d < 64; d <<= 1) {
        s += __shfl_xor(s, d, 64);
        ss += __shfl_xor(ss, d, 64);
    }
    __shared__ float ps[4], pss[4];
    if (lane == 0) { ps[wv] = s; pss[wv] = ss; }
    __syncthreads();
    float S = ps[0] + ps[1] + ps[2] + ps[3];
    float SS = pss[0] + pss[1] + pss[2] + pss[3];
    float m = S * (1.f / DM);
    float var = SS * (1.f / DM) - m * m;
    float inv = rsqrtf(fmaxf(var, 0.f) + 1e-5f);
    s4v st;
#pragma unroll
    for (int k = 0; k < 4; ++k) st[k] = (short)f2s((v[k] - m) * inv);
    *(s4v*)&out[base + tid * 4] = st;
}

extern "C" void kernel_launch(void* const* d_in, const int* in_sizes, int n_in,
                              void* d_out, int out_size, void* d_ws, size_t ws_size,
                              hipStream_t stream) {
    const float* z1ss  = (const float*)d_in[0];
    const float* uss   = (const float*)d_in[1];
    const float* z0    = (const float*)d_in[2];
    const float* pos   = (const float*)d_in[3];
    const float* qkv_w = (const float*)d_in[4];
    const float* r_w   = (const float*)d_in[5];
    const float* rwb   = (const float*)d_in[6];
    const float* rrb   = (const float*)d_in[7];
    const float* o_w   = (const float*)d_in[8];
    const float* o_b   = (const float*)d_in[9];
    const float* ff1_w = (const float*)d_in[10];
    const float* ff1_b = (const float*)d_in[11];
    const float* ff2_w = (const float*)d_in[12];
    const float* ff2_b = (const float*)d_in[13];

    u16* ws = (u16*)d_ws;
    u16* catT     = ws;                         // (4, 1024, 1024)  4M
    u16* avT      = ws + 4194304;               // (4, 512, 1024)   2M
    u16* pre1T    = ws + 6291456;               // (4, 512, 1024)   2M (reused as pre2T)
    u16* xT       = ws + 8388608;               // (4, 512, 1024)   2M
    u16* outT     = ws + 10485760;              // (4, 512, 1024)   2M
    u16* posT     = ws + 12582912;              // (256, 1024)      0.25M
    u16* rT       = ws + 12845056;              // (256, 1024)      0.25M
    u16* whT      = ws + 13107200;              // (4, 1024, 3072)  12M (reused as hT 8M)
    u16* hT       = whT;
    u16* pre2T    = pre1T;
    // total ~51.4 MB

    dim3 tblk(32, 8);

    trans_f2b<<<dim3(16, 32, BSZ), tblk, 0, stream>>>(z0, (long)DM * MLEN, MLEN, 0,
                                                      catT, (long)KLEN * DM, DM, 0);
    trans_f2b<<<dim3(16, 32, BSZ), tblk, 0, stream>>>(z1ss, (long)DM * QLEN, QLEN, 0,
                                                      catT, (long)KLEN * DM, DM, MLEN);
    trans_f2b<<<dim3(8, 32, 1), tblk, 0, stream>>>(pos, 0, KLEN, KLEN - WIN,
                                                   posT, 0, DM, 0);

    // w_headsT = (qkv_w @ cat + uss)^T
    gemm_mfma<128><<<dim3(KLEN / 128, (3 * DM) / 128, BSZ), 256, 0, stream>>>(
        qkv_w, catT, (long)KLEN * DM, whT, (long)KLEN * 3 * DM,
        3 * DM, DM, nullptr, nullptr, 0, uss, (long)3 * DM * KLEN, KLEN, 0);

    // r_usedT = (r_w @ pos[:,768:1024])^T
    gemm_mfma<64><<<dim3(WIN / 64, DM / 128, 1), 256, 0, stream>>>(
        r_w, posT, 0, rT, 0,
        DM, DM, nullptr, nullptr, 0, nullptr, 0, 0, 0);

    attn_kernel<<<dim3(QLEN, BSZ), 256, 0, stream>>>(whT, rT, rwb, rrb, avT);

    // pre1T = (o_w @ attn_vec + o_b + z1ss)^T
    gemm_mfma<64><<<dim3(QLEN / 64, DM / 128, BSZ), 256, 0, stream>>>(
        o_w, avT, (long)QLEN * DM, pre1T, (long)QLEN * DM,
        DM, DM, o_b, nullptr, 0, z1ss, (long)DM * QLEN, QLEN, 0);

    ln_kernel<<<dim3(QLEN, BSZ), 256, 0, stream>>>(pre1T, xT);

    // hT = relu(ff1_w @ x + ff1_b)^T
    gemm_mfma<128><<<dim3(QLEN / 128, DI / 128, BSZ), 256, 0, stream>>>(
        ff1_w, xT, (long)QLEN * DM, hT, (long)QLEN * DI,
        DI, DM, ff1_b, nullptr, 0, nullptr, 0, 0, 1);

    // pre2T = (ff2_w @ h + ff2_b)^T + xT
    gemm_mfma<64><<<dim3(QLEN / 64, DM / 128, BSZ), 256, 0, stream>>>(
        ff2_w, hT, (long)QLEN * DI, pre2T, (long)QLEN * DM,
        DM, DI, ff2_b, xT, (long)QLEN * DM, nullptr, 0, 0, 0);

    ln_kernel<<<dim3(QLEN, BSZ), 256, 0, stream>>>(pre2T, outT);

    trans_b2f<<<dim3(32, 16, BSZ), tblk, 0, stream>>>(outT, (long)QLEN * DM, DM,
                                                      (float*)d_out, (long)DM * QLEN, QLEN);
}

// Round 6
// 602.584 us; speedup vs baseline: 7.2911x; 1.0843x over previous
//
#include <hip/hip_runtime.h>
#include <hip/hip_bf16.h>

typedef unsigned short u16;
typedef __attribute__((ext_vector_type(8))) short s8v;
typedef __attribute__((ext_vector_type(4))) short s4v;
typedef __attribute__((ext_vector_type(4))) float f4v;

__device__ __forceinline__ float s2f(u16 s) {
    unsigned int u = ((unsigned int)s) << 16;
    return __builtin_bit_cast(float, u);
}
__device__ __forceinline__ u16 f2s(float f) {
    __hip_bfloat16 h = __float2bfloat16(f);
    return __builtin_bit_cast(u16, h);
}

// async global->LDS DMA, 16 B per lane; LDS dst must be lane-linear (wave-uniform base + lane*16)
__device__ __forceinline__ void gl2lds16(const u16* g, u16* l) {
    __builtin_amdgcn_global_load_lds((const __attribute__((address_space(1))) void*)g,
                                     (__attribute__((address_space(3))) void*)l, 16, 0, 0);
}

#define BSZ 4
#define DM 1024
#define QLEN 512
#define MLEN 512
#define KLEN 1024
#define DI 4096
#define NH 16
#define DH 64
#define WIN 256   // valid keys: j = i+257 .. i+512

// ---- f32 -> bf16 weight conversion ----
__global__ __launch_bounds__(256) void conv_w(const float* __restrict__ src,
                                              u16* __restrict__ dst, int n4) {
    int i = blockIdx.x * 256 + threadIdx.x;
    if (i < n4) {
        f4v v = *(const f4v*)&src[(size_t)i * 4];
        s4v o;
#pragma unroll
        for (int k = 0; k < 4; ++k) o[k] = (short)f2s(v[k]);
        *(s4v*)&dst[(size_t)i * 4] = o;
    }
}

// ---- transpose f32 (feature-major) -> bf16 (position-major) ----
__global__ __launch_bounds__(256) void trans_f2b(
    const float* __restrict__ src, long sS, int ldS, int colOff,
    u16* __restrict__ dst, long sD, int ldD, int rowOff)
{
    __shared__ float tile[32][33];
    int b = blockIdx.z;
    int t0 = blockIdx.x * 32, f0 = blockIdx.y * 32;
    int tx = threadIdx.x, ty = threadIdx.y;   // (32, 8)
#pragma unroll
    for (int p = 0; p < 4; ++p)
        tile[ty + 8 * p][tx] = src[(size_t)b * sS + (size_t)(f0 + ty + 8 * p) * ldS + colOff + t0 + tx];
    __syncthreads();
#pragma unroll
    for (int p = 0; p < 4; ++p)
        dst[(size_t)b * sD + (size_t)(rowOff + t0 + ty + 8 * p) * ldD + f0 + tx] = f2s(tile[tx][ty + 8 * p]);
}

// ---- transpose bf16 (position-major) -> f32 (feature-major) ----
__global__ __launch_bounds__(256) void trans_b2f(
    const u16* __restrict__ src, long sS, int ldS,
    float* __restrict__ dst, long sD, int ldD)
{
    __shared__ float tile[32][33];
    int b = blockIdx.z;
    int t0 = blockIdx.x * 32, f0 = blockIdx.y * 32;
    int tx = threadIdx.x, ty = threadIdx.y;
#pragma unroll
    for (int p = 0; p < 4; ++p)
        tile[ty + 8 * p][tx] = s2f(src[(size_t)b * sS + (size_t)(f0 + ty + 8 * p) * ldS + t0 + tx]);
    __syncthreads();
#pragma unroll
    for (int p = 0; p < 4; ++p)
        dst[(size_t)b * sD + (size_t)(t0 + ty + 8 * p) * ldD + f0 + tx] = tile[tx][ty + 8 * p];
}

// ---- MFMA GEMM (m97-style): C^T(N x M) = A(M x K, bf16) @ B^T(N x K, bf16) ----
// global_load_lds(16B) staging; XOR-swizzled LDS (chunk q^(row&7)) -> conflict-free frag reads.
// SPLIT>1: atomicAdd f32 partials into fOut[n*M+m]. SPLIT==1: bf16 C with bias/uss/relu epilogue.
template<int BN, int SPLIT>
__global__ __launch_bounds__(256) void gemm_bt(
    const u16* __restrict__ A,
    const u16* __restrict__ B,
    u16* __restrict__ C,
    float* __restrict__ fOut,
    int M, int K,
    const float* __restrict__ bias,
    const float* __restrict__ uss,   // f32 [b][3072][1024], n = b*1024 + t
    int relu)
{
    constexpr int BM = 128, BK = 64;
    constexpr int MI = (BN == 128) ? 4 : 2;
    constexpr int NI = 4;
    const int n0 = blockIdx.x * BN, m0 = blockIdx.y * BM;
    const int Ks = K / SPLIT;
    const int kbeg = blockIdx.z * Ks;
    __shared__ __align__(16) u16 As[BM * BK];
    __shared__ __align__(16) u16 Bs[BN * BK];
    const int tid = threadIdx.x, lane = tid & 63, wv = tid >> 6;
    const int l15 = lane & 15, quad = lane >> 4;
    const int wm = (BN == 128) ? (wv >> 1) * 64 : wv * 32;
    const int wn = (BN == 128) ? (wv & 1) * 64 : 0;
    f4v acc[MI][NI] = {};
    for (int kk = kbeg; kk < kbeg + Ks; kk += BK) {
        __syncthreads();   // previous tile fully consumed
#pragma unroll
        for (int p = 0; p < (BM * 8) / 256; ++p) {
            int c = p * 256 + tid, r = c >> 3, q = c & 7, qs = q ^ (r & 7);
            gl2lds16(&A[(size_t)(m0 + r) * K + kk + qs * 8], &As[c * 8]);
        }
#pragma unroll
        for (int p = 0; p < (BN * 8) / 256; ++p) {
            int c = p * 256 + tid, r = c >> 3, q = c & 7, qs = q ^ (r & 7);
            gl2lds16(&B[(size_t)(n0 + r) * K + kk + qs * 8], &Bs[c * 8]);
        }
        __syncthreads();   // drains vmcnt -> tile staged
#pragma unroll
        for (int k0 = 0; k0 < BK; k0 += 32) {
            s8v af[MI], bf[NI];
#pragma unroll
            for (int mi = 0; mi < MI; ++mi) {
                int r = wm + mi * 16 + l15;
                af[mi] = *(const s8v*)&As[r * BK + ((((k0 >> 3) + quad) ^ (r & 7)) << 3)];
            }
#pragma unroll
            for (int ni = 0; ni < NI; ++ni) {
                int r = wn + ni * 16 + l15;
                bf[ni] = *(const s8v*)&Bs[r * BK + ((((k0 >> 3) + quad) ^ (r & 7)) << 3)];
            }
#pragma unroll
            for (int mi = 0; mi < MI; ++mi)
#pragma unroll
                for (int ni = 0; ni < NI; ++ni)
                    acc[mi][ni] = __builtin_amdgcn_mfma_f32_16x16x32_bf16(af[mi], bf[ni], acc[mi][ni], 0, 0, 0);
        }
    }
    if (SPLIT > 1) {
#pragma unroll
        for (int mi = 0; mi < MI; ++mi) {
            int m = m0 + wm + mi * 16 + quad * 4;
#pragma unroll
            for (int ni = 0; ni < NI; ++ni) {
                int n = n0 + wn + ni * 16 + l15;
                float* dst = &fOut[(size_t)n * M + m];
#pragma unroll
                for (int r2 = 0; r2 < 4; ++r2) atomicAdd(dst + r2, acc[mi][ni][r2]);
            }
        }
    } else {
#pragma unroll
        for (int mi = 0; mi < MI; ++mi) {
            int m = m0 + wm + mi * 16 + quad * 4;
            float bv[4] = {0.f, 0.f, 0.f, 0.f};
            if (bias) {
#pragma unroll
                for (int r2 = 0; r2 < 4; ++r2) bv[r2] = bias[m + r2];
            }
#pragma unroll
            for (int ni = 0; ni < NI; ++ni) {
                int n = n0 + wn + ni * 16 + l15;
                float o[4];
#pragma unroll
                for (int r2 = 0; r2 < 4; ++r2) o[r2] = acc[mi][ni][r2] + bv[r2];
                if (uss) {
                    int b = n >> 10, t = n & 1023;
#pragma unroll
                    for (int r2 = 0; r2 < 4; ++r2)
                        o[r2] += uss[((size_t)b * 3072 + m + r2) * 1024 + t];
                }
                if (relu) {
#pragma unroll
                    for (int r2 = 0; r2 < 4; ++r2) o[r2] = fmaxf(o[r2], 0.f);
                }
                s4v st;
#pragma unroll
                for (int r2 = 0; r2 < 4; ++r2) st[r2] = (short)f2s(o[r2]);
                *(s4v*)&C[(size_t)n * M + m] = st;
            }
        }
    }
}

// ---- fused banded attention, position-major (unchanged from r5) ----
__global__ __launch_bounds__(256) void attn_kernel(
    const u16* __restrict__ WHT,      // (BSZ, KLEN, 3*DM) bf16
    const u16* __restrict__ RT,       // (WIN, DM) bf16
    const float* __restrict__ rwb, const float* __restrict__ rrb,
    u16* __restrict__ avT)            // (BSZ, QLEN, DM) bf16
{
    int i = blockIdx.x, b = blockIdx.y;
    const u16* W = WHT + (size_t)b * KLEN * (3 * DM);
    __shared__ float qac[DM], qbd[DM];
    __shared__ float sm[NH][260];
    __shared__ float obuf[4][DM];
    int tid = threadIdx.x, lane = tid & 63, wv = tid >> 6;
    {
        int f = tid * 4;
        s4v q4 = *(const s4v*)&W[(size_t)(MLEN + i) * (3 * DM) + f];
#pragma unroll
        for (int k = 0; k < 4; ++k) {
            float qv = s2f((u16)q4[k]);
            qac[f + k] = qv + rwb[f + k];
            qbd[f + k] = qv + rrb[f + k];
        }
    }
    __syncthreads();
    int f0 = lane * 16;
    float qa[16], qb[16];
#pragma unroll
    for (int e = 0; e < 16; ++e) { qa[e] = qac[f0 + e]; qb[e] = qbd[f0 + e]; }
    int n = lane >> 2;
    for (int jj = 0; jj < 64; ++jj) {
        int t = wv * 64 + jj;
        const u16* Krow = W + (size_t)(i + WIN + 1 + t) * (3 * DM) + DM;
        const u16* Rrow = RT + (size_t)t * DM;
        float s = 0.f;
#pragma unroll
        for (int c = 0; c < 2; ++c) {
            s8v kv = *(const s8v*)&Krow[f0 + c * 8];
            s8v rv = *(const s8v*)&Rrow[f0 + c * 8];
#pragma unroll
            for (int e = 0; e < 8; ++e) {
                s += qa[c * 8 + e] * s2f((u16)kv[e]);
                s += qb[c * 8 + e] * s2f((u16)rv[e]);
            }
        }
        s += __shfl_xor(s, 1, 64);
        s += __shfl_xor(s, 2, 64);
        if ((lane & 3) == 0) sm[n][t] = s * 0.125f;
    }
    __syncthreads();
#pragma unroll
    for (int hh = 0; hh < 4; ++hh) {
        int nh = wv * 4 + hh;
        f4v v = *(const f4v*)&sm[nh][lane * 4];
        float mx = fmaxf(fmaxf(v[0], v[1]), fmaxf(v[2], v[3]));
#pragma unroll
        for (int d = 1; d < 64; d <<= 1) mx = fmaxf(mx, __shfl_xor(mx, d, 64));
        f4v e;
#pragma unroll
        for (int k = 0; k < 4; ++k) e[k] = __expf(v[k] - mx);
        float sum = e[0] + e[1] + e[2] + e[3];
#pragma unroll
        for (int d = 1; d < 64; d <<= 1) sum += __shfl_xor(sum, d, 64);
        float inv = 1.f / sum;
#pragma unroll
        for (int k = 0; k < 4; ++k) e[k] *= inv;
        *(f4v*)&sm[nh][lane * 4] = e;
    }
    __syncthreads();
    float acc[16];
#pragma unroll
    for (int e = 0; e < 16; ++e) acc[e] = 0.f;
    for (int jj = 0; jj < 64; ++jj) {
        int t = wv * 64 + jj;
        const u16* Vrow = W + (size_t)(i + WIN + 1 + t) * (3 * DM) + 2 * DM;
        float p = sm[n][t];
#pragma unroll
        for (int c = 0; c < 2; ++c) {
            s8v vv = *(const s8v*)&Vrow[f0 + c * 8];
#pragma unroll
            for (int e = 0; e < 8; ++e) acc[c * 8 + e] += p * s2f((u16)vv[e]);
        }
    }
#pragma unroll
    for (int c = 0; c < 4; ++c) {
        f4v o;
#pragma unroll
        for (int k = 0; k < 4; ++k) o[k] = acc[c * 4 + k];
        *(f4v*)&obuf[wv][f0 + c * 4] = o;
    }
    __syncthreads();
    {
        int f = tid * 4;
        f4v o0 = *(const f4v*)&obuf[0][f], o1 = *(const f4v*)&obuf[1][f];
        f4v o2 = *(const f4v*)&obuf[2][f], o3 = *(const f4v*)&obuf[3][f];
        s4v st;
#pragma unroll
        for (int k = 0; k < 4; ++k) st[k] = (short)f2s(o0[k] + o1[k] + o2[k] + o3[k]);
        *(s4v*)&avT[((size_t)b * QLEN + i) * DM + f] = st;
    }
}

// ---- layernorm: out = LN(P_f32 + bias + res_bf16), row-contiguous ----
// resMode 1: res row = b*1024 + 512 + q (z1 rows of catT); resMode 0: res row = n (xT)
__global__ __launch_bounds__(256) void ln_f(
    const float* __restrict__ P, const float* __restrict__ bias,
    const u16* __restrict__ res, int resMode, u16* __restrict__ out)
{
    int n = blockIdx.x, tid = threadIdx.x;
    int lane = tid & 63, wv = tid >> 6;
    int f = tid * 4;
    int rrow = resMode ? (((n >> 9) * 2 + 1) * 512 + (n & 511)) : n;
    f4v pv = *(const f4v*)&P[(size_t)n * DM + f];
    s4v rv = *(const s4v*)&res[(size_t)rrow * DM + f];
    f4v bv = *(const f4v*)&bias[f];
    float v[4];
#pragma unroll
    for (int k = 0; k < 4; ++k) v[k] = pv[k] + bv[k] + s2f((u16)rv[k]);
    float s = v[0] + v[1] + v[2] + v[3];
    float ss = v[0] * v[0] + v[1] * v[1] + v[2] * v[2] + v[3] * v[3];
#pragma unroll
    for (int d = 1; d < 64; d <<= 1) {
        s += __shfl_xor(s, d, 64);
        ss += __shfl_xor(ss, d, 64);
    }
    __shared__ float ps[4], pss[4];
    if (lane == 0) { ps[wv] = s; pss[wv] = ss; }
    __syncthreads();
    float S = ps[0] + ps[1] + ps[2] + ps[3];
    float SS = pss[0] + pss[1] + pss[2] + pss[3];
    float m = S * (1.f / DM);
    float var = SS * (1.f / DM) - m * m;
    float inv = rsqrtf(fmaxf(var, 0.f) + 1e-5f);
    s4v st;
#pragma unroll
    for (int k = 0; k < 4; ++k) st[k] = (short)f2s((v[k] - m) * inv);
    *(s4v*)&out[(size_t)n * DM + f] = st;
}

extern "C" void kernel_launch(void* const* d_in, const int* in_sizes, int n_in,
                              void* d_out, int out_size, void* d_ws, size_t ws_size,
                              hipStream_t stream) {
    const float* z1ss  = (const float*)d_in[0];
    const float* uss   = (const float*)d_in[1];
    const float* z0    = (const float*)d_in[2];
    const float* pos   = (const float*)d_in[3];
    const float* qkv_w = (const float*)d_in[4];
    const float* r_w   = (const float*)d_in[5];
    const float* rwb   = (const float*)d_in[6];
    const float* rrb   = (const float*)d_in[7];
    const float* o_w   = (const float*)d_in[8];
    const float* o_b   = (const float*)d_in[9];
    const float* ff1_w = (const float*)d_in[10];
    const float* ff1_b = (const float*)d_in[11];
    const float* ff2_w = (const float*)d_in[12];
    const float* ff2_b = (const float*)d_in[13];

    u16* ws = (u16*)d_ws;
    u16* wQ   = ws;             // 3072x1024   3145728
    u16* wR   = ws + 3145728;   // 1024x1024   1048576
    u16* wO   = ws + 4194304;   // 1024x1024   1048576
    u16* wF1  = ws + 5242880;   // 4096x1024   4194304
    u16* wF2  = ws + 9437184;   // 1024x4096   4194304
    u16* catT = ws + 13631488;  // (4,1024,1024) 4194304 ; later aliased as outT
    u16* whT  = ws + 17825792;  // (4,1024,3072) 12582912 ; later aliased as hT
    u16* posT = ws + 30408704;  // (256,1024)  262144
    u16* rT   = ws + 30670848;  // (256,1024)  262144
    u16* avT  = ws + 30932992;  // (2048,1024) 2097152
    u16* xT   = ws + 33030144;  // (2048,1024) 2097152
    float* pref = (float*)(ws + 35127296);  // 2048x1024 f32 (pre1 then pre2)
    u16* hT   = whT;            // (2048,4096)
    u16* outT = catT;           // (2048,1024)
    // total 39321600 u16 = 78.6 MB

    dim3 tblk(32, 8);

    // weights f32 -> bf16
    conv_w<<<3072, 256, 0, stream>>>(qkv_w, wQ, 786432);
    conv_w<<<1024, 256, 0, stream>>>(r_w,   wR, 262144);
    conv_w<<<1024, 256, 0, stream>>>(o_w,   wO, 262144);
    conv_w<<<4096, 256, 0, stream>>>(ff1_w, wF1, 1048576);
    conv_w<<<4096, 256, 0, stream>>>(ff2_w, wF2, 1048576);

    // activations -> position-major bf16
    trans_f2b<<<dim3(16, 32, BSZ), tblk, 0, stream>>>(z0, (long)DM * MLEN, MLEN, 0,
                                                      catT, (long)KLEN * DM, DM, 0);
    trans_f2b<<<dim3(16, 32, BSZ), tblk, 0, stream>>>(z1ss, (long)DM * QLEN, QLEN, 0,
                                                      catT, (long)KLEN * DM, DM, MLEN);
    trans_f2b<<<dim3(8, 32, 1), tblk, 0, stream>>>(pos, 0, KLEN, KLEN - WIN,
                                                   posT, 0, DM, 0);

    // qkv: whT(4096 x 3072) = (qkv_w @ cat)^T + uss^T   — 768 blocks
    gemm_bt<128, 1><<<dim3(32, 24, 1), 256, 0, stream>>>(
        wQ, catT, whT, nullptr, 3 * DM, DM, nullptr, uss, 0);

    // r: rT(256 x 1024) = (r_w @ pos[:,768:])^T   — 32 blocks
    gemm_bt<64, 1><<<dim3(4, 8, 1), 256, 0, stream>>>(
        wR, posT, rT, nullptr, DM, DM, nullptr, nullptr, 0);

    // attention -> avT (2048 x 1024)
    attn_kernel<<<dim3(QLEN, BSZ), 256, 0, stream>>>(whT, rT, rwb, rrb, avT);

    // o-proj split-2 atomic: pref += (o_w @ av)^T   — 512 blocks
    hipMemsetAsync(pref, 0, (size_t)2048 * 1024 * 4, stream);
    gemm_bt<64, 2><<<dim3(32, 8, 2), 256, 0, stream>>>(
        wO, avT, nullptr, pref, DM, DM, nullptr, nullptr, 0);

    // xT = LN(pref + o_b + z1 residual from catT)
    ln_f<<<2048, 256, 0, stream>>>(pref, o_b, catT, 1, xT);

    // ff1: hT(2048 x 4096) = relu(ff1_w @ x + ff1_b)^T   — 512 blocks
    gemm_bt<128, 1><<<dim3(16, 32, 1), 256, 0, stream>>>(
        wF1, xT, hT, nullptr, DI, DM, ff1_b, nullptr, 1);

    // ff2 split-4 atomic: pref += (ff2_w @ h)^T   — 512 blocks
    hipMemsetAsync(pref, 0, (size_t)2048 * 1024 * 4, stream);
    gemm_bt<128, 4><<<dim3(16, 8, 4), 256, 0, stream>>>(
        wF2, hT, nullptr, pref, DM, DI, nullptr, nullptr, 0);

    // outT = LN(pref + ff2_b + xT)
    ln_f<<<2048, 256, 0, stream>>>(pref, ff2_b, xT, 0, outT);

    // d_out[b][d][q] = outT[(b,q)][d]  (f32)
    trans_b2f<<<dim3(32, 16, BSZ), tblk, 0, stream>>>(outT, (long)QLEN * DM, DM,
                                                      (float*)d_out, (long)DM * QLEN, QLEN);
}

// Round 7
// 504.828 us; speedup vs baseline: 8.7030x; 1.1936x over previous
//
#include <hip/hip_runtime.h>
#include <hip/hip_bf16.h>

typedef unsigned short u16;
typedef __attribute__((ext_vector_type(8))) short s8v;
typedef __attribute__((ext_vector_type(4))) short s4v;
typedef __attribute__((ext_vector_type(4))) float f4v;

__device__ __forceinline__ float s2f(u16 s) {
    unsigned int u = ((unsigned int)s) << 16;
    return __builtin_bit_cast(float, u);
}
__device__ __forceinline__ u16 f2s(float f) {
    __hip_bfloat16 h = __float2bfloat16(f);
    return __builtin_bit_cast(u16, h);
}

// async global->LDS DMA, 16 B per lane; LDS dst must be lane-linear
__device__ __forceinline__ void gl2lds16(const u16* g, u16* l) {
    __builtin_amdgcn_global_load_lds((const __attribute__((address_space(1))) void*)g,
                                     (__attribute__((address_space(3))) void*)l, 16, 0, 0);
}

#define BSZ 4
#define DM 1024
#define QLEN 512
#define MLEN 512
#define KLEN 1024
#define DI 4096
#define NH 16
#define DH 64
#define WIN 256   // valid keys: j = i+257 .. i+512

// ---- f32 -> bf16 weight conversion ----
__global__ __launch_bounds__(256) void conv_w(const float* __restrict__ src,
                                              u16* __restrict__ dst, int n4) {
    int i = blockIdx.x * 256 + threadIdx.x;
    if (i < n4) {
        f4v v = *(const f4v*)&src[(size_t)i * 4];
        s4v o;
#pragma unroll
        for (int k = 0; k < 4; ++k) o[k] = (short)f2s(v[k]);
        *(s4v*)&dst[(size_t)i * 4] = o;
    }
}

// ---- transpose f32 (feature-major) -> bf16 (position-major) ----
__global__ __launch_bounds__(256) void trans_f2b(
    const float* __restrict__ src, long sS, int ldS, int colOff,
    u16* __restrict__ dst, long sD, int ldD, int rowOff)
{
    __shared__ float tile[32][33];
    int b = blockIdx.z;
    int t0 = blockIdx.x * 32, f0 = blockIdx.y * 32;
    int tx = threadIdx.x, ty = threadIdx.y;   // (32, 8)
#pragma unroll
    for (int p = 0; p < 4; ++p)
        tile[ty + 8 * p][tx] = src[(size_t)b * sS + (size_t)(f0 + ty + 8 * p) * ldS + colOff + t0 + tx];
    __syncthreads();
#pragma unroll
    for (int p = 0; p < 4; ++p)
        dst[(size_t)b * sD + (size_t)(rowOff + t0 + ty + 8 * p) * ldD + f0 + tx] = f2s(tile[tx][ty + 8 * p]);
}

// ---- transpose bf16 (position-major) -> f32 (feature-major) ----
__global__ __launch_bounds__(256) void trans_b2f(
    const u16* __restrict__ src, long sS, int ldS,
    float* __restrict__ dst, long sD, int ldD)
{
    __shared__ float tile[32][33];
    int b = blockIdx.z;
    int t0 = blockIdx.x * 32, f0 = blockIdx.y * 32;
    int tx = threadIdx.x, ty = threadIdx.y;
#pragma unroll
    for (int p = 0; p < 4; ++p)
        tile[ty + 8 * p][tx] = s2f(src[(size_t)b * sS + (size_t)(f0 + ty + 8 * p) * ldS + t0 + tx]);
    __syncthreads();
#pragma unroll
    for (int p = 0; p < 4; ++p)
        dst[(size_t)b * sD + (size_t)(t0 + ty + 8 * p) * ldD + f0 + tx] = tile[tx][ty + 8 * p];
}

// ---- MFMA GEMM (m97-style): C^T(N x M) = A(M x K, bf16) @ B^T(N x K, bf16) ----
template<int BN, int SPLIT>
__global__ __launch_bounds__(256) void gemm_bt(
    const u16* __restrict__ A,
    const u16* __restrict__ B,
    u16* __restrict__ C,
    float* __restrict__ fOut,
    int M, int K,
    const float* __restrict__ bias,
    const float* __restrict__ uss,   // f32 [b][3072][1024], n = b*1024 + t
    int relu)
{
    constexpr int BM = 128, BK = 64;
    constexpr int MI = (BN == 128) ? 4 : 2;
    constexpr int NI = 4;
    const int n0 = blockIdx.x * BN, m0 = blockIdx.y * BM;
    const int Ks = K / SPLIT;
    const int kbeg = blockIdx.z * Ks;
    __shared__ __align__(16) u16 As[BM * BK];
    __shared__ __align__(16) u16 Bs[BN * BK];
    const int tid = threadIdx.x, lane = tid & 63, wv = tid >> 6;
    const int l15 = lane & 15, quad = lane >> 4;
    const int wm = (BN == 128) ? (wv >> 1) * 64 : wv * 32;
    const int wn = (BN == 128) ? (wv & 1) * 64 : 0;
    f4v acc[MI][NI] = {};
    for (int kk = kbeg; kk < kbeg + Ks; kk += BK) {
        __syncthreads();
#pragma unroll
        for (int p = 0; p < (BM * 8) / 256; ++p) {
            int c = p * 256 + tid, r = c >> 3, q = c & 7, qs = q ^ (r & 7);
            gl2lds16(&A[(size_t)(m0 + r) * K + kk + qs * 8], &As[c * 8]);
        }
#pragma unroll
        for (int p = 0; p < (BN * 8) / 256; ++p) {
            int c = p * 256 + tid, r = c >> 3, q = c & 7, qs = q ^ (r & 7);
            gl2lds16(&B[(size_t)(n0 + r) * K + kk + qs * 8], &Bs[c * 8]);
        }
        __syncthreads();
#pragma unroll
        for (int k0 = 0; k0 < BK; k0 += 32) {
            s8v af[MI], bf[NI];
#pragma unroll
            for (int mi = 0; mi < MI; ++mi) {
                int r = wm + mi * 16 + l15;
                af[mi] = *(const s8v*)&As[r * BK + ((((k0 >> 3) + quad) ^ (r & 7)) << 3)];
            }
#pragma unroll
            for (int ni = 0; ni < NI; ++ni) {
                int r = wn + ni * 16 + l15;
                bf[ni] = *(const s8v*)&Bs[r * BK + ((((k0 >> 3) + quad) ^ (r & 7)) << 3)];
            }
#pragma unroll
            for (int mi = 0; mi < MI; ++mi)
#pragma unroll
                for (int ni = 0; ni < NI; ++ni)
                    acc[mi][ni] = __builtin_amdgcn_mfma_f32_16x16x32_bf16(af[mi], bf[ni], acc[mi][ni], 0, 0, 0);
        }
    }
    if (SPLIT > 1) {
#pragma unroll
        for (int mi = 0; mi < MI; ++mi) {
            int m = m0 + wm + mi * 16 + quad * 4;
#pragma unroll
            for (int ni = 0; ni < NI; ++ni) {
                int n = n0 + wn + ni * 16 + l15;
                float* dst = &fOut[(size_t)n * M + m];
#pragma unroll
                for (int r2 = 0; r2 < 4; ++r2) atomicAdd(dst + r2, acc[mi][ni][r2]);
            }
        }
    } else {
#pragma unroll
        for (int mi = 0; mi < MI; ++mi) {
            int m = m0 + wm + mi * 16 + quad * 4;
            float bv[4] = {0.f, 0.f, 0.f, 0.f};
            if (bias) {
#pragma unroll
                for (int r2 = 0; r2 < 4; ++r2) bv[r2] = bias[m + r2];
            }
#pragma unroll
            for (int ni = 0; ni < NI; ++ni) {
                int n = n0 + wn + ni * 16 + l15;
                float o[4];
#pragma unroll
                for (int r2 = 0; r2 < 4; ++r2) o[r2] = acc[mi][ni][r2] + bv[r2];
                if (uss) {
                    int b = n >> 10, t = n & 1023;
#pragma unroll
                    for (int r2 = 0; r2 < 4; ++r2)
                        o[r2] += uss[((size_t)b * 3072 + m + r2) * 1024 + t];
                }
                if (relu) {
#pragma unroll
                    for (int r2 = 0; r2 < 4; ++r2) o[r2] = fmaxf(o[r2], 0.f);
                }
                s4v st;
#pragma unroll
                for (int r2 = 0; r2 < 4; ++r2) st[r2] = (short)f2s(o[r2]);
                *(s4v*)&C[(size_t)n * M + m] = st;
            }
        }
    }
}

// ---- MFMA banded flash attention ----
// block = (qtile of 16, head n, batch b); 256 thr = 4 waves.
// Keys for tile: j = j0 .. j0+271 (j0 = i0+257), c = j - j0; band: c - qi in [0,255].
// BD handled by scattering RQ[qi][t'] into S[qi][qi+t'] over an S pre-init of -1e30.
#define QT 16
#define KT 272    // 17 tiles of 16
#define KROW 72   // K LDS row stride (u16): 2-way banks
#define VROW 280  // V^T LDS row stride (u16): 2-way banks
#define SROW 272  // S row stride (f32)
#define PROW 280  // P row stride (u16)
__global__ __launch_bounds__(256) void attn_mfma(
    const u16* __restrict__ WHT,      // (BSZ, KLEN, 3*DM) bf16
    const u16* __restrict__ RT,       // (WIN, DM) bf16
    const float* __restrict__ rwb, const float* __restrict__ rrb,
    u16* __restrict__ avT)            // (BSZ, QLEN, DM) bf16
{
    __shared__ __align__(16) u16  sKV[KT * KROW];   // 39168 B; phase2 holds V^T [64][VROW]
    __shared__ __align__(16) float sS[QT * SROW];   // 17408 B
    __shared__ __align__(16) u16  sP[QT * PROW];    //  8960 B   (total = 65536 B exactly)

    const int qt = blockIdx.x, n = blockIdx.y, b = blockIdx.z;
    const int i0 = qt * QT, j0 = i0 + WIN + 1;
    const int tid = threadIdx.x, lane = tid & 63, wv = tid >> 6;
    const int l15 = lane & 15, quad = lane >> 4;
    const u16* W = WHT + (size_t)b * KLEN * (3 * DM);

    // Q fragments (A-operand rows = l15 = qi), biases baked in
    s8v qac[2], qbd[2];
    {
        int qrow = MLEN + i0 + l15;
#pragma unroll
        for (int kc = 0; kc < 2; ++kc) {
            int col = n * DH + kc * 32 + quad * 8;
            s8v qv = *(const s8v*)&W[(size_t)qrow * (3 * DM) + col];
            s8v a, c;
#pragma unroll
            for (int e = 0; e < 8; ++e) {
                float qf = s2f((u16)qv[e]);
                a[e] = (short)f2s(qf + rwb[col + e]);
                c[e] = (short)f2s(qf + rrb[col + e]);
            }
            qac[kc] = a; qbd[kc] = c;
        }
    }

    // stage K tile: row c, 8 chunks of 8 u16; j clamped (garbage lands only in masked cells)
    for (int t = tid; t < KT * 8; t += 256) {
        int r = t >> 3, q = t & 7;
        int j = j0 + r; if (j > KLEN - 1) j = KLEN - 1;
        *(s8v*)&sKV[r * KROW + q * 8] = *(const s8v*)&W[(size_t)j * (3 * DM) + DM + n * DH + q * 8];
    }
    // init S to -1e30 (mask default)
    for (int t = tid; t < QT * SROW; t += 256) sS[t] = -1e30f;
    __syncthreads();

    // RQ = rr_q @ R^T, scattered into S at [qi][qi + t']  (4 ci' tiles per wave)
#pragma unroll
    for (int cc = 0; cc < 4; ++cc) {
        int ci = wv + cc * 4;
        f4v acc = {};
#pragma unroll
        for (int kc = 0; kc < 2; ++kc) {
            s8v bf = *(const s8v*)&RT[(size_t)(ci * 16 + l15) * DM + n * DH + kc * 32 + quad * 8];
            acc = __builtin_amdgcn_mfma_f32_16x16x32_bf16(qbd[kc], bf, acc, 0, 0, 0);
        }
#pragma unroll
        for (int r2 = 0; r2 < 4; ++r2) {
            int qi = quad * 4 + r2;
            sS[qi * SROW + qi + ci * 16 + l15] = acc[r2];
        }
    }
    __syncthreads();

    // S += Q·K^T  (ci tiles round-robin over waves)
    for (int ci = wv; ci < 17; ci += 4) {
        f4v acc = {};
#pragma unroll
        for (int kc = 0; kc < 2; ++kc) {
            s8v bf = *(const s8v*)&sKV[(ci * 16 + l15) * KROW + kc * 32 + quad * 8];
            acc = __builtin_amdgcn_mfma_f32_16x16x32_bf16(qac[kc], bf, acc, 0, 0, 0);
        }
#pragma unroll
        for (int r2 = 0; r2 < 4; ++r2) {
            int qi = quad * 4 + r2;
            sS[qi * SROW + ci * 16 + l15] += acc[r2];
        }
    }
    __syncthreads();

    // stage V^T into sKV as [d][VROW]: thread group q=tid>>5 owns d-chunk, r fast for bank spread
    {
        int q = tid >> 5, r0 = tid & 31;
        for (int k = 0; k < 9; ++k) {
            int r = r0 + 32 * k;
            if (r < KT) {
                int j = j0 + r; if (j > KLEN - 1) j = KLEN - 1;
                s8v vv = *(const s8v*)&W[(size_t)j * (3 * DM) + 2 * DM + n * DH + q * 8];
#pragma unroll
                for (int e = 0; e < 8; ++e)
                    sKV[(q * 8 + e) * VROW + r] = (u16)vv[e];
            }
        }
    }

    // softmax: 16 groups of 16 lanes, group g owns row g
    {
        int g = tid >> 4, l = tid & 15;
        float vals[17], mx = -1e30f;
#pragma unroll
        for (int k = 0; k < 17; ++k) {
            float s = sS[g * SROW + l + 16 * k] * 0.125f;
            vals[k] = s; mx = fmaxf(mx, s);
        }
#pragma unroll
        for (int d = 1; d < 16; d <<= 1) mx = fmaxf(mx, __shfl_xor(mx, d, 16));
        float sum = 0.f;
#pragma unroll
        for (int k = 0; k < 17; ++k) { vals[k] = __expf(vals[k] - mx); sum += vals[k]; }
#pragma unroll
        for (int d = 1; d < 16; d <<= 1) sum += __shfl_xor(sum, d, 16);
        float inv = 1.f / sum;
#pragma unroll
        for (int k = 0; k < 17; ++k) sP[g * PROW + l + 16 * k] = f2s(vals[k] * inv);
    }
    __syncthreads();

    // O = P @ V : wave wv owns d-tile ni=wv; k = 272 -> 8 full chunks + 16-wide tail
    f4v o = {};
    for (int kc = 0; kc < 9; ++kc) {
        s8v a = {}, bb = {};
        if (kc < 8) {
            a  = *(const s8v*)&sP[l15 * PROW + kc * 32 + quad * 8];
            bb = *(const s8v*)&sKV[(wv * 16 + l15) * VROW + kc * 32 + quad * 8];
        } else if (quad < 2) {
            a  = *(const s8v*)&sP[l15 * PROW + 256 + quad * 8];
            bb = *(const s8v*)&sKV[(wv * 16 + l15) * VROW + 256 + quad * 8];
        }
        o = __builtin_amdgcn_mfma_f32_16x16x32_bf16(a, bb, o, 0, 0, 0);
    }
#pragma unroll
    for (int r2 = 0; r2 < 4; ++r2) {
        int qi = quad * 4 + r2;
        avT[((size_t)b * QLEN + i0 + qi) * DM + n * DH + wv * 16 + l15] = f2s(o[r2]);
    }
}

// ---- layernorm: out = LN(P_f32 + bias + res_bf16), row-contiguous ----
__global__ __launch_bounds__(256) void ln_f(
    const float* __restrict__ P, const float* __restrict__ bias,
    const u16* __restrict__ res, int resMode, u16* __restrict__ out)
{
    int n = blockIdx.x, tid = threadIdx.x;
    int lane = tid & 63, wv = tid >> 6;
    int f = tid * 4;
    int rrow = resMode ? (((n >> 9) * 2 + 1) * 512 + (n & 511)) : n;
    f4v pv = *(const f4v*)&P[(size_t)n * DM + f];
    s4v rv = *(const s4v*)&res[(size_t)rrow * DM + f];
    f4v bv = *(const f4v*)&bias[f];
    float v[4];
#pragma unroll
    for (int k = 0; k < 4; ++k) v[k] = pv[k] + bv[k] + s2f((u16)rv[k]);
    float s = v[0] + v[1] + v[2] + v[3];
    float ss = v[0] * v[0] + v[1] * v[1] + v[2] * v[2] + v[3] * v[3];
#pragma unroll
    for (int d = 1; d < 64; d <<= 1) {
        s += __shfl_xor(s, d, 64);
        ss += __shfl_xor(ss, d, 64);
    }
    __shared__ float ps[4], pss[4];
    if (lane == 0) { ps[wv] = s; pss[wv] = ss; }
    __syncthreads();
    float S = ps[0] + ps[1] + ps[2] + ps[3];
    float SS = pss[0] + pss[1] + pss[2] + pss[3];
    float m = S * (1.f / DM);
    float var = SS * (1.f / DM) - m * m;
    float inv = rsqrtf(fmaxf(var, 0.f) + 1e-5f);
    s4v st;
#pragma unroll
    for (int k = 0; k < 4; ++k) st[k] = (short)f2s((v[k] - m) * inv);
    *(s4v*)&out[(size_t)n * DM + f] = st;
}

extern "C" void kernel_launch(void* const* d_in, const int* in_sizes, int n_in,
                              void* d_out, int out_size, void* d_ws, size_t ws_size,
                              hipStream_t stream) {
    const float* z1ss  = (const float*)d_in[0];
    const float* uss   = (const float*)d_in[1];
    const float* z0    = (const float*)d_in[2];
    const float* pos   = (const float*)d_in[3];
    const float* qkv_w = (const float*)d_in[4];
    const float* r_w   = (const float*)d_in[5];
    const float* rwb   = (const float*)d_in[6];
    const float* rrb   = (const float*)d_in[7];
    const float* o_w   = (const float*)d_in[8];
    const float* o_b   = (const float*)d_in[9];
    const float* ff1_w = (const float*)d_in[10];
    const float* ff1_b = (const float*)d_in[11];
    const float* ff2_w = (const float*)d_in[12];
    const float* ff2_b = (const float*)d_in[13];

    u16* ws = (u16*)d_ws;
    u16* wQ   = ws;             // 3072x1024
    u16* wR   = ws + 3145728;
    u16* wO   = ws + 4194304;
    u16* wF1  = ws + 5242880;
    u16* wF2  = ws + 9437184;
    u16* catT = ws + 13631488;  // (4,1024,1024); later aliased as outT
    u16* whT  = ws + 17825792;  // (4,1024,3072); later aliased as hT
    u16* posT = ws + 30408704;  // (256,1024)
    u16* rT   = ws + 30670848;  // (256,1024)
    u16* avT  = ws + 30932992;  // (2048,1024)
    u16* xT   = ws + 33030144;  // (2048,1024)
    float* pref = (float*)(ws + 35127296);  // 2048x1024 f32
    u16* hT   = whT;
    u16* outT = catT;

    dim3 tblk(32, 8);

    conv_w<<<3072, 256, 0, stream>>>(qkv_w, wQ, 786432);
    conv_w<<<1024, 256, 0, stream>>>(r_w,   wR, 262144);
    conv_w<<<1024, 256, 0, stream>>>(o_w,   wO, 262144);
    conv_w<<<4096, 256, 0, stream>>>(ff1_w, wF1, 1048576);
    conv_w<<<4096, 256, 0, stream>>>(ff2_w, wF2, 1048576);

    trans_f2b<<<dim3(16, 32, BSZ), tblk, 0, stream>>>(z0, (long)DM * MLEN, MLEN, 0,
                                                      catT, (long)KLEN * DM, DM, 0);
    trans_f2b<<<dim3(16, 32, BSZ), tblk, 0, stream>>>(z1ss, (long)DM * QLEN, QLEN, 0,
                                                      catT, (long)KLEN * DM, DM, MLEN);
    trans_f2b<<<dim3(8, 32, 1), tblk, 0, stream>>>(pos, 0, KLEN, KLEN - WIN,
                                                   posT, 0, DM, 0);

    // qkv: whT(4096 x 3072) = (qkv_w @ cat)^T + uss^T
    gemm_bt<128, 1><<<dim3(32, 24, 1), 256, 0, stream>>>(
        wQ, catT, whT, nullptr, 3 * DM, DM, nullptr, uss, 0);

    // r: rT(256 x 1024) = (r_w @ pos[:,768:])^T
    gemm_bt<64, 1><<<dim3(4, 8, 1), 256, 0, stream>>>(
        wR, posT, rT, nullptr, DM, DM, nullptr, nullptr, 0);

    // MFMA banded attention -> avT
    attn_mfma<<<dim3(QLEN / QT, NH, BSZ), 256, 0, stream>>>(whT, rT, rwb, rrb, avT);

    // o-proj split-2 atomic
    hipMemsetAsync(pref, 0, (size_t)2048 * 1024 * 4, stream);
    gemm_bt<64, 2><<<dim3(32, 8, 2), 256, 0, stream>>>(
        wO, avT, nullptr, pref, DM, DM, nullptr, nullptr, 0);

    ln_f<<<2048, 256, 0, stream>>>(pref, o_b, catT, 1, xT);

    // ff1
    gemm_bt<128, 1><<<dim3(16, 32, 1), 256, 0, stream>>>(
        wF1, xT, hT, nullptr, DI, DM, ff1_b, nullptr, 1);

    // ff2 split-4 atomic
    hipMemsetAsync(pref, 0, (size_t)2048 * 1024 * 4, stream);
    gemm_bt<128, 4><<<dim3(16, 8, 4), 256, 0, stream>>>(
        wF2, hT, nullptr, pref, DM, DI, nullptr, nullptr, 0);

    ln_f<<<2048, 256, 0, stream>>>(pref, ff2_b, xT, 0, outT);

    trans_b2f<<<dim3(32, 16, BSZ), tblk, 0, stream>>>(outT, (long)QLEN * DM, DM,
                                                      (float*)d_out, (long)DM * QLEN, QLEN);
}